// Round 5
// baseline (182.183 us; speedup 1.0000x reference)
//
#include <hip/hip_runtime.h>

#define E_TOT 500000
#define N_NODES 100000
#define RB 128
#define NBH2 ((N_NODES + RB - 1) / RB)  // 782 row-blocks per half
#define CSTR 264                        // C_lds row stride in shorts

typedef __attribute__((ext_vector_type(8))) short short8;
typedef __attribute__((ext_vector_type(4))) float f32x4;

__device__ __forceinline__ unsigned short f2bf(float f) {
  union { float f; unsigned u; } x; x.f = f;
  unsigned r = x.u + 0x7fffu + ((x.u >> 16) & 1u);
  return (unsigned short)(r >> 16);
}

__device__ __forceinline__ float bf2f(unsigned short s) {
  union { unsigned u; float f; } x; x.u = ((unsigned)s) << 16;
  return x.f;
}

// w1 (f32 [256][512]) -> w1r2 bf16 [half][kb2=0..31][n=0..255][j=0..7]
__global__ void k_repack_w1h(const float* __restrict__ w1,
                             unsigned short* __restrict__ w1r2) {
  int o = blockIdx.x * 256 + threadIdx.x;  // 131072 total
  int half = o >> 16;
  int kb = (o >> 11) & 31;
  int n = (o >> 3) & 255;
  int j = o & 7;
  w1r2[o] = f2bf(w1[n * 512 + half * 256 + kb * 8 + j]);
}

// U'[n] = zsrc[n] @ W1s^T + b1 (half 0) ; V[n] = zdst[n] @ W1d^T (half 1)
// Single-barrier structure: B in regs, A panel staged once (swizzled LDS).
__global__ __launch_bounds__(512, 4) void k_node_gemm(
    const float* __restrict__ zsrc, const float* __restrict__ zdst,
    const unsigned short* __restrict__ w1r2, const float* __restrict__ b1,
    unsigned short* __restrict__ Uo, unsigned short* __restrict__ Vo) {
  __shared__ __align__(16) char smem[RB * CSTR * 2];  // 67584 B
  unsigned short* A_lds = (unsigned short*)smem;  // [kb=0..31][row^ (kb&7)][8] 64 KB
  unsigned short* C_lds = (unsigned short*)smem;  // [128][CSTR] overlay

  const int bi = blockIdx.x;
  const int half = (bi >= NBH2) ? 1 : 0;
  const int n0 = (bi - half * NBH2) * RB;
  const float* Z = half ? zdst : zsrc;
  unsigned short* O = half ? Vo : Uo;

  const unsigned tid = threadIdx.x;
  const unsigned l = tid & 63u;
  const unsigned w = tid >> 6;
  const unsigned l15 = l & 15u;
  const unsigned lg = l >> 4;

  // ---- B fragments: direct global->reg (w1r2 is in fragment order, L2-hot)
  const unsigned short* bbase = w1r2 + half * 65536u;
  short8 breg[4][2][2];  // [c][ks][nf]
#pragma unroll
  for (int c = 0; c < 4; ++c)
#pragma unroll
    for (int ks = 0; ks < 2; ++ks)
#pragma unroll
      for (int nf = 0; nf < 2; ++nf) {
        unsigned kb2 = (unsigned)c * 8u + (unsigned)ks * 4u + lg;
        unsigned col = w * 32u + (unsigned)nf * 16u + l15;
        breg[c][ks][nf] = *(const short8*)(bbase + (kb2 * 256u + col) * 8u);
      }

  // ---- A panel: issue ALL global loads (256 B/lane in flight) ----
  const unsigned ar = tid >> 3;   // 0..63
  const unsigned kbl = tid & 7u;  // becomes kb low-3
  int r0 = n0 + (int)ar;
  int r1 = n0 + (int)ar + 64;
  if (r0 > N_NODES - 1) r0 = N_NODES - 1;
  if (r1 > N_NODES - 1) r1 = N_NODES - 1;
  const float* p0 = Z + (long)r0 * 256 + kbl * 8u;
  const float* p1 = Z + (long)r1 * 256 + kbl * 8u;

  f32x4 ga[4][2][2];  // [c][rowset][16B-half]
#pragma unroll
  for (int c = 0; c < 4; ++c) {
    ga[c][0][0] = ((const f32x4*)(p0 + c * 64))[0];
    ga[c][0][1] = ((const f32x4*)(p0 + c * 64))[1];
    ga[c][1][0] = ((const f32x4*)(p1 + c * 64))[0];
    ga[c][1][1] = ((const f32x4*)(p1 + c * 64))[1];
  }

  f32x4 acc[8][2];
#pragma unroll
  for (int mf = 0; mf < 8; ++mf)
#pragma unroll
    for (int nf = 0; nf < 2; ++nf) acc[mf][nf] = (f32x4){0.f, 0.f, 0.f, 0.f};

  // convert + swizzled ds_write (kb-octet spread across bank quads by row^kbl)
#pragma unroll
  for (int c = 0; c < 4; ++c) {
    unsigned kb = (unsigned)c * 8u + kbl;
#pragma unroll
    for (int rs = 0; rs < 2; ++rs) {
      unsigned row = ar + (unsigned)rs * 64u;
      short8 sa;
      sa[0] = (short)f2bf(ga[c][rs][0].x); sa[1] = (short)f2bf(ga[c][rs][0].y);
      sa[2] = (short)f2bf(ga[c][rs][0].z); sa[3] = (short)f2bf(ga[c][rs][0].w);
      sa[4] = (short)f2bf(ga[c][rs][1].x); sa[5] = (short)f2bf(ga[c][rs][1].y);
      sa[6] = (short)f2bf(ga[c][rs][1].z); sa[7] = (short)f2bf(ga[c][rs][1].w);
      *(short8*)&A_lds[kb * 1024u + ((row ^ kbl) * 8u)] = sa;
    }
  }

  __syncthreads();  // the ONLY pre-epilogue barrier

  // ---- MFMA phase: 64 ds_read_b128 + 128 MFMA per wave, no barriers ----
#pragma unroll
  for (int c = 0; c < 4; ++c) {
#pragma unroll
    for (int ks = 0; ks < 2; ++ks) {
      unsigned kb = (unsigned)c * 8u + (unsigned)ks * 4u + lg;
      unsigned x = kb & 7u;
#pragma unroll
      for (int mf = 0; mf < 8; ++mf) {
        short8 afr =
            *(const short8*)&A_lds[kb * 1024u + (((mf * 16u + l15) ^ x) * 8u)];
        acc[mf][0] = __builtin_amdgcn_mfma_f32_16x16x32_bf16(
            afr, breg[c][ks][0], acc[mf][0], 0, 0, 0);
        acc[mf][1] = __builtin_amdgcn_mfma_f32_16x16x32_bf16(
            afr, breg[c][ks][1], acc[mf][1], 0, 0, 0);
      }
    }
  }

  // ---- epilogue: bias, cast, LDS transpose, coalesced 16B stores ----
  float b1v[2];
#pragma unroll
  for (int nf = 0; nf < 2; ++nf)
    b1v[nf] = half ? 0.f : b1[w * 32u + nf * 16u + l15];

  __syncthreads();  // MFMA ds_reads done -> overlay C on A
#pragma unroll
  for (int mf = 0; mf < 8; ++mf) {
#pragma unroll
    for (int nf = 0; nf < 2; ++nf) {
#pragma unroll
      for (int r = 0; r < 4; ++r) {
        unsigned row = mf * 16u + lg * 4u + (unsigned)r;
        unsigned col = w * 32u + (unsigned)nf * 16u + l15;
        C_lds[row * CSTR + col] = f2bf(acc[mf][nf][r] + b1v[nf]);
      }
    }
  }
  __syncthreads();
#pragma unroll
  for (int k = 0; k < 8; ++k) {
    unsigned u = tid + (unsigned)k * 512u;
    unsigned row = u >> 5;
    unsigned cu = u & 31u;
    if (n0 + (int)row < N_NODES) {
      short8 vv = *(const short8*)&C_lds[row * CSTR + cu * 8u];
      *(short8*)(O + (long)(n0 + row) * 256 + cu * 8u) = vv;
    }
  }
}

// per edge: out = sigmoid( w2 . relu(U'[row] + V[col]) + b2 )
// 3-stage pipeline: idx(e+2) || rows(e+1) || compute(e)
#define EK_ITER 16
__global__ __launch_bounds__(256, 6) void k_edge(
    const unsigned short* __restrict__ U, const unsigned short* __restrict__ V,
    const int* __restrict__ eli, const float* __restrict__ w2,
    const float* __restrict__ b2, float* __restrict__ out) {
  const int tid = threadIdx.x;
  const int g = tid >> 4;
  const int j = tid & 15;
  float w2v[16];
#pragma unroll
  for (int q = 0; q < 8; ++q) {
    w2v[q] = w2[8 * j + q];
    w2v[8 + q] = w2[128 + 8 * j + q];
  }
  const float b2v = b2[0];
  const long base = (long)blockIdx.x * (16 * EK_ITER) + g;

#define CLAMP_E(k) \
  (((base + 16 * (k)) < E_TOT) ? (base + 16 * (k)) : (long)(E_TOT - 1))

  long eP = CLAMP_E(0);
  int rA = eli[eP], cA = eli[E_TOT + eP];
  long eQ = CLAMP_E(1);
  int rB = eli[eQ], cB = eli[E_TOT + eQ];
  short8 uA0 = *(const short8*)(U + (long)rA * 256 + 8 * j);
  short8 uA1 = *(const short8*)(U + (long)rA * 256 + 128 + 8 * j);
  short8 vA0 = *(const short8*)(V + (long)cA * 256 + 8 * j);
  short8 vA1 = *(const short8*)(V + (long)cA * 256 + 128 + 8 * j);
  short8 uB0, uB1, vB0, vB1;

#pragma unroll
  for (int it2 = 0; it2 < EK_ITER / 2; ++it2) {
    {
      long eN = CLAMP_E(2 * it2 + 2);
      int rN = eli[eN], cN = eli[E_TOT + eN];
      uB0 = *(const short8*)(U + (long)rB * 256 + 8 * j);
      uB1 = *(const short8*)(U + (long)rB * 256 + 128 + 8 * j);
      vB0 = *(const short8*)(V + (long)cB * 256 + 8 * j);
      vB1 = *(const short8*)(V + (long)cB * 256 + 128 + 8 * j);
      rB = rN; cB = cN;
      float p = 0.f;
#pragma unroll
      for (int q = 0; q < 8; ++q) {
        float a0 = bf2f((unsigned short)uA0[q]) + bf2f((unsigned short)vA0[q]);
        float a1 = bf2f((unsigned short)uA1[q]) + bf2f((unsigned short)vA1[q]);
        p = fmaf(fmaxf(a0, 0.f), w2v[q], p);
        p = fmaf(fmaxf(a1, 0.f), w2v[8 + q], p);
      }
      p += __shfl_xor(p, 1);
      p += __shfl_xor(p, 2);
      p += __shfl_xor(p, 4);
      p += __shfl_xor(p, 8);
      long e = base + 16 * (2 * it2);
      if (j == 0 && e < E_TOT) out[e] = 1.f / (1.f + __expf(-(p + b2v)));
    }
    {
      long eN = CLAMP_E(2 * it2 + 3);
      int rN = eli[eN], cN = eli[E_TOT + eN];
      uA0 = *(const short8*)(U + (long)rB * 256 + 8 * j);
      uA1 = *(const short8*)(U + (long)rB * 256 + 128 + 8 * j);
      vA0 = *(const short8*)(V + (long)cB * 256 + 8 * j);
      vA1 = *(const short8*)(V + (long)cB * 256 + 128 + 8 * j);
      rB = rN; cB = cN;
      float p = 0.f;
#pragma unroll
      for (int q = 0; q < 8; ++q) {
        float a0 = bf2f((unsigned short)uB0[q]) + bf2f((unsigned short)vB0[q]);
        float a1 = bf2f((unsigned short)uB1[q]) + bf2f((unsigned short)vB1[q]);
        p = fmaf(fmaxf(a0, 0.f), w2v[q], p);
        p = fmaf(fmaxf(a1, 0.f), w2v[8 + q], p);
      }
      p += __shfl_xor(p, 1);
      p += __shfl_xor(p, 2);
      p += __shfl_xor(p, 4);
      p += __shfl_xor(p, 8);
      long e = base + 16 * (2 * it2 + 1);
      if (j == 0 && e < E_TOT) out[e] = 1.f / (1.f + __expf(-(p + b2v)));
    }
  }
#undef CLAMP_E
}

extern "C" void kernel_launch(void* const* d_in, const int* in_sizes, int n_in,
                              void* d_out, int out_size, void* d_ws,
                              size_t ws_size, hipStream_t stream) {
  const float* zsrc = (const float*)d_in[0];
  const float* zdst = (const float*)d_in[1];
  const int* eli = (const int*)d_in[2];
  const float* w1 = (const float*)d_in[3];
  const float* b1 = (const float*)d_in[4];
  const float* w2 = (const float*)d_in[5];
  const float* b2 = (const float*)d_in[6];
  float* out = (float*)d_out;

  const size_t uv_bytes = (size_t)N_NODES * 256 * 2;  // 51.2 MB each
  unsigned short* U = (unsigned short*)d_ws;
  unsigned short* V = (unsigned short*)((char*)d_ws + uv_bytes);
  unsigned short* w1r2 = (unsigned short*)((char*)d_ws + 2 * uv_bytes);

  k_repack_w1h<<<512, 256, 0, stream>>>(w1, w1r2);
  k_node_gemm<<<2 * NBH2, 512, 0, stream>>>(zsrc, zdst, w1r2, b1, U, V);
  int nbe = (E_TOT + 16 * EK_ITER - 1) / (16 * EK_ITER);
  k_edge<<<nbe, 256, 0, stream>>>(U, V, eli, w2, b2, out);
}